// Round 5
// baseline (164.223 us; speedup 1.0000x reference)
//
#include <hip/hip_runtime.h>
#include <hip/hip_bf16.h>

// Problem constants (reference: B=2, S=2048, D=1024, H=16, HD=64)
constexpr int Bb = 2, Ss = 2048, Dd = 1024, Hh = 16, HD = 64;
constexpr int Mrows = Bb * Ss;                 // 4096
constexpr float QSCALE = 0.125f * 1.44269504088896f;  // 1/sqrt(HD) * log2(e), folded into Q
constexpr size_t CTX_ELEMS = (size_t)Bb * Hh * Ss * HD;

typedef __attribute__((ext_vector_type(8)))  short        short8;
typedef __attribute__((ext_vector_type(4)))  float        floatx4;
typedef __attribute__((ext_vector_type(16))) float        floatx16;
typedef __attribute__((ext_vector_type(4)))  unsigned int uintx4;
typedef __attribute__((ext_vector_type(8)))  __bf16       bf16x8;

#define DEVI __device__ __forceinline__

DEVI unsigned short f2bf(float f) {
  union { float f; unsigned u; } x; x.f = f;
  return (unsigned short)((x.u + 0x7fffu + ((x.u >> 16) & 1u)) >> 16);   // RNE
}
DEVI float fexp2(float x) {
#if __has_builtin(__builtin_amdgcn_exp2f)
  return __builtin_amdgcn_exp2f(x);
#else
  return __expf(x * 0.6931471805599453f);
#endif
}

// workspace layout (bf16 elems), fast path:
constexpr size_t XE = (size_t)Mrows * Dd;      // 4M per X tensor
constexpr size_t WE = (size_t)Dd * Dd;         // 1M per W tensor
constexpr size_t OFF_W = 3 * XE;               // converted weights
constexpr size_t OFF_O = 3 * XE + 3 * WE;      // Q | K | V^T outputs
constexpr size_t WS_NEED = (OFF_O + 3 * XE) * 2;   // 54 MB

// ---------------------------------------------------------------------------
// fp32 -> bf16 conversion pass (6 tensors)
// ---------------------------------------------------------------------------
__global__ __launch_bounds__(256) void convert_bf16(
    const float* __restrict__ q, const float* __restrict__ k, const float* __restrict__ v,
    const float* __restrict__ wq, const float* __restrict__ wk, const float* __restrict__ wv,
    unsigned short* __restrict__ dst)
{
  const int sel = blockIdx.y;
  const float* src; size_t n, off;
  switch (sel) {
    case 0:  src = q;  n = XE; off = 0;            break;
    case 1:  src = k;  n = XE; off = XE;           break;
    case 2:  src = v;  n = XE; off = 2 * XE;       break;
    case 3:  src = wq; n = WE; off = OFF_W;        break;
    case 4:  src = wk; n = WE; off = OFF_W + WE;   break;
    default: src = wv; n = WE; off = OFF_W + 2*WE; break;
  }
  unsigned short* d = dst + off;
  const size_t stride = (size_t)gridDim.x * blockDim.x;
  for (size_t i = (size_t)blockIdx.x * blockDim.x + threadIdx.x; i < n / 8; i += stride) {
    const floatx4 a = *(const floatx4*)(src + i * 8);
    const floatx4 b = *(const floatx4*)(src + i * 8 + 4);
    short8 o;
    #pragma unroll
    for (int j = 0; j < 4; ++j) { o[j] = (short)f2bf(a[j]); o[4 + j] = (short)f2bf(b[j]); }
    *(short8*)(d + i * 8) = o;
  }
}

// ---------------------------------------------------------------------------
// Shared GEMM epilogue (16x16 layout).
// ---------------------------------------------------------------------------
template<bool SWAP>
DEVI void store_out(floatx4 (&acc)[4][4], const float* __restrict__ bias,
                    unsigned short* __restrict__ out, float oscale,
                    int bm, int bn, int wm, int wn, int lrow, int lg)
{
  if constexpr (!SWAP) {
    #pragma unroll
    for (int ni = 0; ni < 4; ++ni) {
      const int gcol = bn * 128 + wn + ni * 16 + lrow;
      const float bval = bias[gcol];
      const int h = gcol >> 6, hd = gcol & 63;
      #pragma unroll
      for (int mi = 0; mi < 4; ++mi)
        #pragma unroll
        for (int r = 0; r < 4; ++r) {
          const int grow = bm * 128 + wm + mi * 16 + lg * 4 + r;   // = b*S + s
          const int b = grow >> 11, s = grow & 2047;
          out[(((size_t)(b * Hh + h) * Ss + s) << 6) + hd] = f2bf((acc[mi][ni][r] + bval) * oscale);
        }
    }
  } else {
    #pragma unroll
    for (int ni = 0; ni < 4; ++ni)
      #pragma unroll
      for (int r = 0; r < 4; ++r) {
        const int n = bn * 128 + wn + ni * 16 + lg * 4 + r;
        const float bval = bias[n];
        #pragma unroll
        for (int mi = 0; mi < 4; ++mi) {
          const int m = bm * 128 + wm + mi * 16 + lrow;
          out[(size_t)n * Mrows + m] = f2bf(acc[mi][ni][r] + bval);
        }
      }
  }
}

// ---------------------------------------------------------------------------
// Fast GEMM core: global_load_lds(16B), BK=64, XOR-swizzled LDS.
// ---------------------------------------------------------------------------
DEVI void gload16(const unsigned short* g, unsigned short* l) {
  __builtin_amdgcn_global_load_lds(
      (const __attribute__((address_space(1))) unsigned int*)g,
      (__attribute__((address_space(3))) unsigned int*)l, 16, 0, 0);
}

template<bool SWAP>
DEVI void gemm_core_bf16(const unsigned short* __restrict__ X,
                         const unsigned short* __restrict__ W,
                         const float* __restrict__ bias,
                         unsigned short* __restrict__ out, float oscale,
                         unsigned short* As, unsigned short* Bs, int bm, int bn)
{
  const int t = threadIdx.x, wid = t >> 6, lane = t & 63;
  const int lrow = lane & 15, lg = lane >> 4;
  const int wm = (wid >> 1) * 64, wn = (wid & 1) * 64;

  const int srow = lane >> 3;
  const int gch  = (lane & 7) ^ srow;
  const unsigned short* gA = X + (size_t)(bm * 128 + wid * 32 + srow) * Dd + gch * 8;
  const unsigned short* gB = W + (size_t)(bn * 128 + wid * 32 + srow) * Dd + gch * 8;
  unsigned short* lA = As + wid * 4 * 512;
  unsigned short* lB = Bs + wid * 4 * 512;

  floatx4 acc[4][4];
  #pragma unroll
  for (int i = 0; i < 4; ++i)
    #pragma unroll
    for (int j = 0; j < 4; ++j) acc[i][j] = 0.0f;

  for (int k0 = 0; k0 < Dd; k0 += 64) {
    __syncthreads();
    #pragma unroll
    for (int j = 0; j < 4; ++j) {
      gload16(gA + (size_t)j * 8 * Dd + k0, lA + j * 512);
      gload16(gB + (size_t)j * 8 * Dd + k0, lB + j * 512);
    }
    __syncthreads();

    #pragma unroll
    for (int kf = 0; kf < 2; ++kf) {
      bf16x8 af[4], bf[4];
      #pragma unroll
      for (int mi = 0; mi < 4; ++mi) {
        const int row = wm + mi * 16 + lrow;
        const int ch  = ((kf << 2) | lg) ^ (lrow & 7);
        af[mi] = __builtin_bit_cast(bf16x8, *(const short8*)&As[row * 64 + (ch << 3)]);
      }
      #pragma unroll
      for (int ni = 0; ni < 4; ++ni) {
        const int row = wn + ni * 16 + lrow;
        const int ch  = ((kf << 2) | lg) ^ (lrow & 7);
        bf[ni] = __builtin_bit_cast(bf16x8, *(const short8*)&Bs[row * 64 + (ch << 3)]);
      }
      #pragma unroll
      for (int mi = 0; mi < 4; ++mi)
        #pragma unroll
        for (int ni = 0; ni < 4; ++ni) {
          if constexpr (SWAP)
            acc[mi][ni] = __builtin_amdgcn_mfma_f32_16x16x32_bf16(bf[ni], af[mi], acc[mi][ni], 0, 0, 0);
          else
            acc[mi][ni] = __builtin_amdgcn_mfma_f32_16x16x32_bf16(af[mi], bf[ni], acc[mi][ni], 0, 0, 0);
        }
    }
  }
  store_out<SWAP>(acc, bias, out, oscale, bm, bn, wm, wn, lrow, lg);
}

__global__ __launch_bounds__(256, 3) void qkv_gemm_bf16(
    const unsigned short* __restrict__ ws,
    const float* __restrict__ bq, const float* __restrict__ bk, const float* __restrict__ bv,
    unsigned short* __restrict__ outbase)
{
  __shared__ __align__(16) unsigned short As[128 * 64];
  __shared__ __align__(16) unsigned short Bs[128 * 64];

  const int id  = blockIdx.y * 256 + blockIdx.x;
  const int swz = (id & 7) * 96 + (id >> 3);
  const int sel = swz >> 8;
  const int bx  = swz & 255;
  const int bm = bx >> 3, bn = bx & 7;

  const unsigned short* X = ws + (size_t)sel * XE;
  const unsigned short* W = ws + OFF_W + (size_t)sel * WE;
  const float* bias = sel == 0 ? bq : sel == 1 ? bk : bv;
  unsigned short* out = outbase + (size_t)sel * XE;

  if (sel == 2) gemm_core_bf16<true >(X, W, bias, out, 1.0f,   As, Bs, bm, bn);
  else          gemm_core_bf16<false>(X, W, bias, out, sel == 0 ? QSCALE : 1.0f, As, Bs, bm, bn);
}

// ---------------------------------------------------------------------------
// Fallback GEMM (fp32 inputs) — used if ws too small.
// ---------------------------------------------------------------------------
constexpr int APAD = 40;

template<bool SWAP>
DEVI void gemm_core_f32(const float* __restrict__ X, const float* __restrict__ W,
                        const float* __restrict__ bias, unsigned short* __restrict__ out,
                        float oscale, unsigned short* As, unsigned short* Bs, int bm, int bn)
{
  const int t = threadIdx.x, wid = t >> 6, lane = t & 63;
  const int lrow = lane & 15, lg = lane >> 4;
  const int wm = (wid >> 1) * 64, wn = (wid & 1) * 64;

  floatx4 acc[4][4];
  #pragma unroll
  for (int i = 0; i < 4; ++i)
    #pragma unroll
    for (int j = 0; j < 4; ++j) acc[i][j] = 0.0f;

  for (int k0 = 0; k0 < Dd; k0 += 32) {
    __syncthreads();
    #pragma unroll
    for (int half = 0; half < 2; ++half) {
      const int cidx = t + half * 256;
      const int r = cidx >> 2, c = cidx & 3;
      {
        const float* ga = X + (size_t)(bm * 128 + r) * Dd + k0 + c * 8;
        const floatx4 x0 = *(const floatx4*)ga;
        const floatx4 x1 = *(const floatx4*)(ga + 4);
        short8 va;
        #pragma unroll
        for (int j = 0; j < 4; ++j) { va[j] = (short)f2bf(x0[j]); va[4+j] = (short)f2bf(x1[j]); }
        *(short8*)&As[r * APAD + c * 8] = va;
      }
      {
        const float* gb = W + (size_t)(bn * 128 + r) * Dd + k0 + c * 8;
        const floatx4 x0 = *(const floatx4*)gb;
        const floatx4 x1 = *(const floatx4*)(gb + 4);
        short8 vb;
        #pragma unroll
        for (int j = 0; j < 4; ++j) { vb[j] = (short)f2bf(x0[j]); vb[4+j] = (short)f2bf(x1[j]); }
        *(short8*)&Bs[r * APAD + c * 8] = vb;
      }
    }
    __syncthreads();

    bf16x8 af[4], bf[4];
    #pragma unroll
    for (int mi = 0; mi < 4; ++mi)
      af[mi] = __builtin_bit_cast(bf16x8, *(const short8*)&As[(wm + mi * 16 + lrow) * APAD + lg * 8]);
    #pragma unroll
    for (int ni = 0; ni < 4; ++ni)
      bf[ni] = __builtin_bit_cast(bf16x8, *(const short8*)&Bs[(wn + ni * 16 + lrow) * APAD + lg * 8]);

    #pragma unroll
    for (int mi = 0; mi < 4; ++mi)
      #pragma unroll
      for (int ni = 0; ni < 4; ++ni) {
        if constexpr (SWAP)
          acc[mi][ni] = __builtin_amdgcn_mfma_f32_16x16x32_bf16(bf[ni], af[mi], acc[mi][ni], 0, 0, 0);
        else
          acc[mi][ni] = __builtin_amdgcn_mfma_f32_16x16x32_bf16(af[mi], bf[ni], acc[mi][ni], 0, 0, 0);
      }
  }
  store_out<SWAP>(acc, bias, out, oscale, bm, bn, wm, wn, lrow, lg);
}

__global__ __launch_bounds__(256, 2) void qkv_gemm_f32(
    const float* __restrict__ q, const float* __restrict__ k, const float* __restrict__ v,
    const float* __restrict__ wq, const float* __restrict__ wk, const float* __restrict__ wv,
    const float* __restrict__ bq, const float* __restrict__ bk, const float* __restrict__ bv,
    unsigned short* __restrict__ outbase)
{
  __shared__ __align__(16) unsigned short As[128 * APAD];
  __shared__ __align__(16) unsigned short Bs[128 * APAD];

  const int id  = blockIdx.y * 256 + blockIdx.x;
  const int swz = (id & 7) * 96 + (id >> 3);
  const int sel = swz >> 8;
  const int bx  = swz & 255;
  const int bm = bx >> 3, bn = bx & 7;

  const float* X = sel == 0 ? q : sel == 1 ? k : v;
  const float* W = sel == 0 ? wq : sel == 1 ? wk : wv;
  const float* bias = sel == 0 ? bq : sel == 1 ? bk : bv;
  unsigned short* out = outbase + (size_t)sel * XE;

  if (sel == 2) gemm_core_f32<true >(X, W, bias, out, 1.0f, As, Bs, bm, bn);
  else          gemm_core_f32<false>(X, W, bias, out, sel == 0 ? QSCALE : 1.0f, As, Bs, bm, bn);
}

// ---------------------------------------------------------------------------
// Flash attention, 32x32 MFMA, NO LDS / NO barriers: K,V fragments loaded
// directly global->VGPR (each fragment = contiguous 16B of a K row / V^T row,
// coalesced 1KB per instruction; K/V tiles are L1/L2-resident).
// K double-buffered in registers (prefetch 1 tile ahead, static 2-step unroll);
// V issued at tile top, consumed ~400 cycles later in PV.
// Swapped QK^T -> in-register softmax -> cvt_pk + permlane32_swap -> PV.
// ---------------------------------------------------------------------------
constexpr int NT = Ss / 64;   // 32 kv tiles

__global__ __launch_bounds__(256, 2) void attn_fwd(
    const unsigned short* __restrict__ Qw, const unsigned short* __restrict__ Kw,
    const unsigned short* __restrict__ Vw, float* __restrict__ out)
{
  // XCD-bijective swizzle: 512 blocks -> 64-contiguous per XCD.
  const int id  = blockIdx.y * 16 + blockIdx.x;
  const int swz = (id & 7) * 64 + (id >> 3);
  const int qb  = swz & 15, bh = swz >> 4;
  const int b   = bh >> 4, h = bh & 15;

  const int t = threadIdx.x, wid = t >> 6, lane = t & 63;
  const int l31 = lane & 31, hi = lane >> 5;
  const int q0 = qb * 128 + wid * 32;

  const unsigned short* Qb  = Qw + (size_t)bh * (Ss * HD);
  // per-lane folded bases:
  const unsigned short* KbL = Kw + (size_t)bh * (Ss * HD) + (size_t)l31 * 64 + hi * 8;
  const unsigned short* VbL = Vw + (size_t)(h * 64 + l31) * Mrows + b * Ss + hi * 8;

  // Q B-fragments: lane holds Q[q=l31][hd = hs*16 + hi*8 + j]
  bf16x8 qf[4];
  #pragma unroll
  for (int hs = 0; hs < 4; ++hs)
    qf[hs] = __builtin_bit_cast(bf16x8,
        *(const short8*)(Qb + (size_t)(q0 + l31) * 64 + hs * 16 + hi * 8));

  floatx16 ctx[2], lsum;
  ctx[0] = 0.0f; ctx[1] = 0.0f; lsum = 0.0f;

  short8 ones_s;
  #pragma unroll
  for (int j = 0; j < 8; ++j) ones_s[j] = (short)0x3F80;   // bf16 1.0
  const bf16x8 ones = __builtin_bit_cast(bf16x8, ones_s);

  // K fragment (kvb,hs) of tile kv0: rows kvb*32+l31, cols hs*16+hi*8 (16B chunk)
  auto loadK = [&](bf16x8 (&kd)[8], int kv0) {
    #pragma unroll
    for (int kvb = 0; kvb < 2; ++kvb)
      #pragma unroll
      for (int hs = 0; hs < 4; ++hs)
        kd[kvb * 4 + hs] = __builtin_bit_cast(bf16x8,
            *(const short8*)(KbL + (size_t)(kv0 + kvb * 32) * 64 + hs * 16));
  };
  // V^T fragment (nb,ks): row hd = nb*32+l31, cols kv0+ks*16+hi*8
  auto loadV = [&](bf16x8 (&vd)[8], int kv0) {
    #pragma unroll
    for (int nb = 0; nb < 2; ++nb)
      #pragma unroll
      for (int ks = 0; ks < 4; ++ks)
        vd[nb * 4 + ks] = __builtin_bit_cast(bf16x8,
            *(const short8*)(VbL + (size_t)(nb * 32) * Mrows + kv0 + ks * 16));
  };

  auto tile = [&](bf16x8 (&kc)[8], bf16x8 (&kn)[8], int it) {
    const int kv0 = it * 64;
    bf16x8 vb[8];
    loadV(vb, kv0);                                   // used in PV (~400 cyc later)
    const int kvn = (it + 1 < NT) ? kv0 + 64 : 0;     // uniform clamp (in-bounds)
    loadK(kn, kvn);                                   // prefetch next K tile

    // ---- S^T = K Q^T : col=q=l31, row=kv (from registers, no wait) ----
    floatx16 s[2];
    s[0] = 0.0f; s[1] = 0.0f;
    __builtin_amdgcn_s_setprio(1);
    #pragma unroll
    for (int kvb = 0; kvb < 2; ++kvb)
      #pragma unroll
      for (int hs = 0; hs < 4; ++hs)
        s[kvb] = __builtin_amdgcn_mfma_f32_32x32x16_bf16(kc[kvb * 4 + hs], qf[hs], s[kvb], 0, 0, 0);
    __builtin_amdgcn_s_setprio(0);

    // ---- exp2 -> pack bf16 -> permlane half-swap -> PV ----
    #pragma unroll
    for (int kvb = 0; kvb < 2; ++kvb) {
      float p[16];
      #pragma unroll
      for (int r = 0; r < 16; ++r) p[r] = fexp2(s[kvb][r]);
      unsigned int c[8];
      #pragma unroll
      for (int i = 0; i < 8; ++i)
        asm("v_cvt_pk_bf16_f32 %0, %1, %2" : "=v"(c[i]) : "v"(p[2 * i]), "v"(p[2 * i + 1]));

      #pragma unroll
      for (int ks2 = 0; ks2 < 2; ++ks2) {
        unsigned int w0 = c[4 * ks2 + 0], w2 = c[4 * ks2 + 2];
        unsigned int w1 = c[4 * ks2 + 1], w3 = c[4 * ks2 + 3];
        asm("v_permlane32_swap_b32 %0, %1" : "+v"(w0), "+v"(w2));
        asm("v_permlane32_swap_b32 %0, %1" : "+v"(w1), "+v"(w3));
        uintx4 paw; paw[0] = w0; paw[1] = w1; paw[2] = w2; paw[3] = w3;
        const bf16x8 pa = __builtin_bit_cast(bf16x8, paw);

        const int ks = kvb * 2 + ks2;
        __builtin_amdgcn_s_setprio(1);
        lsum = __builtin_amdgcn_mfma_f32_32x32x16_bf16(pa, ones, lsum, 0, 0, 0);
        ctx[0] = __builtin_amdgcn_mfma_f32_32x32x16_bf16(pa, vb[ks],     ctx[0], 0, 0, 0);
        ctx[1] = __builtin_amdgcn_mfma_f32_32x32x16_bf16(pa, vb[4 + ks], ctx[1], 0, 0, 0);
        __builtin_amdgcn_s_setprio(0);
      }
    }
  };

  bf16x8 kA[8], kB[8];
  loadK(kA, 0);
  for (int it = 0; it < NT; it += 2) {   // static 2-step unroll: no dynamic reg indexing
    tile(kA, kB, it);
    tile(kB, kA, it + 1);
  }

  // ---- epilogue: normalize, write context [B,H,S,HD] + attn_output [B,S,D] ----
  #pragma unroll
  for (int r = 0; r < 16; ++r) {
    const float inv = 1.0f / lsum[r];
    const int qrow = q0 + (r & 3) + 8 * (r >> 2) + 4 * hi;
    #pragma unroll
    for (int nb = 0; nb < 2; ++nb) {
      const int hd = nb * 32 + l31;
      const float val = ctx[nb][r] * inv;
      out[((size_t)bh * Ss + qrow) * 64 + hd] = val;
      out[CTX_ELEMS + (((size_t)(b * Ss + qrow)) << 10) + (h << 6) + hd] = val;
    }
  }
}

// ---------------------------------------------------------------------------
extern "C" void kernel_launch(void* const* d_in, const int* in_sizes, int n_in,
                              void* d_out, int out_size, void* d_ws, size_t ws_size,
                              hipStream_t stream) {
  const float* q  = (const float*)d_in[0];
  const float* k  = (const float*)d_in[1];
  const float* v  = (const float*)d_in[2];
  const float* wq = (const float*)d_in[3];
  const float* bq = (const float*)d_in[4];
  const float* wk = (const float*)d_in[5];
  const float* bk = (const float*)d_in[6];
  const float* wv = (const float*)d_in[7];
  const float* bv = (const float*)d_in[8];
  unsigned short* ws = (unsigned short*)d_ws;
  float* out = (float*)d_out;

  if (ws_size >= WS_NEED) {
    convert_bf16<<<dim3(256, 6), 256, 0, stream>>>(q, k, v, wq, wk, wv, ws);
    qkv_gemm_bf16<<<dim3(256, 3), 256, 0, stream>>>(ws, bq, bk, bv, ws + OFF_O);
    attn_fwd<<<dim3(16, 32), 256, 0, stream>>>(ws + OFF_O, ws + OFF_O + XE, ws + OFF_O + 2 * XE, out);
  } else {
    qkv_gemm_f32<<<dim3(256, 3), 256, 0, stream>>>(q, k, v, wq, wk, wv, bq, bk, bv, ws);
    attn_fwd<<<dim3(16, 32), 256, 0, stream>>>(ws, ws + XE, ws + 2 * XE, out);
  }
}

// Round 6
// 93.282 us; speedup vs baseline: 1.7605x; 1.7605x over previous
//
#include <hip/hip_runtime.h>
#include <hip/hip_bf16.h>

// Problem constants (reference: B=2, S=2048, D=1024, H=16, HD=64)
constexpr int Bb = 2, Ss = 2048, Dd = 1024, Hh = 16, HD = 64;
constexpr int Mrows = Bb * Ss;                 // 4096
constexpr float QSCALE = 0.125f * 1.44269504088896f;  // 1/sqrt(HD) * log2(e), folded into Q
constexpr size_t CTX_ELEMS = (size_t)Bb * Hh * Ss * HD;

typedef __attribute__((ext_vector_type(8)))  short        short8;
typedef __attribute__((ext_vector_type(4)))  float        floatx4;
typedef __attribute__((ext_vector_type(16))) float        floatx16;
typedef __attribute__((ext_vector_type(4)))  unsigned int uintx4;
typedef __attribute__((ext_vector_type(8)))  __bf16       bf16x8;

#define DEVI __device__ __forceinline__

DEVI unsigned short f2bf(float f) {
  union { float f; unsigned u; } x; x.f = f;
  return (unsigned short)((x.u + 0x7fffu + ((x.u >> 16) & 1u)) >> 16);   // RNE
}
DEVI float fexp2(float x) {
#if __has_builtin(__builtin_amdgcn_exp2f)
  return __builtin_amdgcn_exp2f(x);
#else
  return __expf(x * 0.6931471805599453f);
#endif
}

// workspace layout (bf16 elems), fast path:
constexpr size_t XE = (size_t)Mrows * Dd;      // 4M per X tensor
constexpr size_t WE = (size_t)Dd * Dd;         // 1M per W tensor
constexpr size_t OFF_W = 3 * XE;               // converted weights
constexpr size_t OFF_O = 3 * XE + 3 * WE;      // Q | K | V^T outputs
constexpr size_t WS_NEED = (OFF_O + 3 * XE) * 2;   // 54 MB

// ---------------------------------------------------------------------------
// fp32 -> bf16 conversion pass (6 tensors)
// ---------------------------------------------------------------------------
__global__ __launch_bounds__(256) void convert_bf16(
    const float* __restrict__ q, const float* __restrict__ k, const float* __restrict__ v,
    const float* __restrict__ wq, const float* __restrict__ wk, const float* __restrict__ wv,
    unsigned short* __restrict__ dst)
{
  const int sel = blockIdx.y;
  const float* src; size_t n, off;
  switch (sel) {
    case 0:  src = q;  n = XE; off = 0;            break;
    case 1:  src = k;  n = XE; off = XE;           break;
    case 2:  src = v;  n = XE; off = 2 * XE;       break;
    case 3:  src = wq; n = WE; off = OFF_W;        break;
    case 4:  src = wk; n = WE; off = OFF_W + WE;   break;
    default: src = wv; n = WE; off = OFF_W + 2*WE; break;
  }
  unsigned short* d = dst + off;
  const size_t stride = (size_t)gridDim.x * blockDim.x;
  for (size_t i = (size_t)blockIdx.x * blockDim.x + threadIdx.x; i < n / 8; i += stride) {
    const floatx4 a = *(const floatx4*)(src + i * 8);
    const floatx4 b = *(const floatx4*)(src + i * 8 + 4);
    short8 o;
    #pragma unroll
    for (int j = 0; j < 4; ++j) { o[j] = (short)f2bf(a[j]); o[4 + j] = (short)f2bf(b[j]); }
    *(short8*)(d + i * 8) = o;
  }
}

// ---------------------------------------------------------------------------
// Shared GEMM epilogue (16x16 layout).
// ---------------------------------------------------------------------------
template<bool SWAP>
DEVI void store_out(floatx4 (&acc)[4][4], const float* __restrict__ bias,
                    unsigned short* __restrict__ out, float oscale,
                    int bm, int bn, int wm, int wn, int lrow, int lg)
{
  if constexpr (!SWAP) {
    #pragma unroll
    for (int ni = 0; ni < 4; ++ni) {
      const int gcol = bn * 128 + wn + ni * 16 + lrow;
      const float bval = bias[gcol];
      const int h = gcol >> 6, hd = gcol & 63;
      #pragma unroll
      for (int mi = 0; mi < 4; ++mi)
        #pragma unroll
        for (int r = 0; r < 4; ++r) {
          const int grow = bm * 128 + wm + mi * 16 + lg * 4 + r;   // = b*S + s
          const int b = grow >> 11, s = grow & 2047;
          out[(((size_t)(b * Hh + h) * Ss + s) << 6) + hd] = f2bf((acc[mi][ni][r] + bval) * oscale);
        }
    }
  } else {
    #pragma unroll
    for (int ni = 0; ni < 4; ++ni)
      #pragma unroll
      for (int r = 0; r < 4; ++r) {
        const int n = bn * 128 + wn + ni * 16 + lg * 4 + r;
        const float bval = bias[n];
        #pragma unroll
        for (int mi = 0; mi < 4; ++mi) {
          const int m = bm * 128 + wm + mi * 16 + lrow;
          out[(size_t)n * Mrows + m] = f2bf(acc[mi][ni][r] + bval);
        }
      }
  }
}

// ---------------------------------------------------------------------------
// Fast GEMM core: global_load_lds(16B), BK=64, XOR-swizzled LDS.
// ---------------------------------------------------------------------------
DEVI void gload16(const unsigned short* g, unsigned short* l) {
  __builtin_amdgcn_global_load_lds(
      (const __attribute__((address_space(1))) unsigned int*)g,
      (__attribute__((address_space(3))) unsigned int*)l, 16, 0, 0);
}

template<bool SWAP>
DEVI void gemm_core_bf16(const unsigned short* __restrict__ X,
                         const unsigned short* __restrict__ W,
                         const float* __restrict__ bias,
                         unsigned short* __restrict__ out, float oscale,
                         unsigned short* As, unsigned short* Bs, int bm, int bn)
{
  const int t = threadIdx.x, wid = t >> 6, lane = t & 63;
  const int lrow = lane & 15, lg = lane >> 4;
  const int wm = (wid >> 1) * 64, wn = (wid & 1) * 64;

  const int srow = lane >> 3;
  const int gch  = (lane & 7) ^ srow;
  const unsigned short* gA = X + (size_t)(bm * 128 + wid * 32 + srow) * Dd + gch * 8;
  const unsigned short* gB = W + (size_t)(bn * 128 + wid * 32 + srow) * Dd + gch * 8;
  unsigned short* lA = As + wid * 4 * 512;
  unsigned short* lB = Bs + wid * 4 * 512;

  floatx4 acc[4][4];
  #pragma unroll
  for (int i = 0; i < 4; ++i)
    #pragma unroll
    for (int j = 0; j < 4; ++j) acc[i][j] = 0.0f;

  for (int k0 = 0; k0 < Dd; k0 += 64) {
    __syncthreads();
    #pragma unroll
    for (int j = 0; j < 4; ++j) {
      gload16(gA + (size_t)j * 8 * Dd + k0, lA + j * 512);
      gload16(gB + (size_t)j * 8 * Dd + k0, lB + j * 512);
    }
    __syncthreads();

    #pragma unroll
    for (int kf = 0; kf < 2; ++kf) {
      bf16x8 af[4], bf[4];
      #pragma unroll
      for (int mi = 0; mi < 4; ++mi) {
        const int row = wm + mi * 16 + lrow;
        const int ch  = ((kf << 2) | lg) ^ (lrow & 7);
        af[mi] = __builtin_bit_cast(bf16x8, *(const short8*)&As[row * 64 + (ch << 3)]);
      }
      #pragma unroll
      for (int ni = 0; ni < 4; ++ni) {
        const int row = wn + ni * 16 + lrow;
        const int ch  = ((kf << 2) | lg) ^ (lrow & 7);
        bf[ni] = __builtin_bit_cast(bf16x8, *(const short8*)&Bs[row * 64 + (ch << 3)]);
      }
      #pragma unroll
      for (int mi = 0; mi < 4; ++mi)
        #pragma unroll
        for (int ni = 0; ni < 4; ++ni) {
          if constexpr (SWAP)
            acc[mi][ni] = __builtin_amdgcn_mfma_f32_16x16x32_bf16(bf[ni], af[mi], acc[mi][ni], 0, 0, 0);
          else
            acc[mi][ni] = __builtin_amdgcn_mfma_f32_16x16x32_bf16(af[mi], bf[ni], acc[mi][ni], 0, 0, 0);
        }
    }
  }
  store_out<SWAP>(acc, bias, out, oscale, bm, bn, wm, wn, lrow, lg);
}

__global__ __launch_bounds__(256, 3) void qkv_gemm_bf16(
    const unsigned short* __restrict__ ws,
    const float* __restrict__ bq, const float* __restrict__ bk, const float* __restrict__ bv,
    unsigned short* __restrict__ outbase)
{
  __shared__ __align__(16) unsigned short As[128 * 64];
  __shared__ __align__(16) unsigned short Bs[128 * 64];

  const int id  = blockIdx.y * 256 + blockIdx.x;
  const int swz = (id & 7) * 96 + (id >> 3);
  const int sel = swz >> 8;
  const int bx  = swz & 255;
  const int bm = bx >> 3, bn = bx & 7;

  const unsigned short* X = ws + (size_t)sel * XE;
  const unsigned short* W = ws + OFF_W + (size_t)sel * WE;
  const float* bias = sel == 0 ? bq : sel == 1 ? bk : bv;
  unsigned short* out = outbase + (size_t)sel * XE;

  if (sel == 2) gemm_core_bf16<true >(X, W, bias, out, 1.0f,   As, Bs, bm, bn);
  else          gemm_core_bf16<false>(X, W, bias, out, sel == 0 ? QSCALE : 1.0f, As, Bs, bm, bn);
}

// ---------------------------------------------------------------------------
// Fallback GEMM (fp32 inputs) — used if ws too small.
// ---------------------------------------------------------------------------
constexpr int APAD = 40;

template<bool SWAP>
DEVI void gemm_core_f32(const float* __restrict__ X, const float* __restrict__ W,
                        const float* __restrict__ bias, unsigned short* __restrict__ out,
                        float oscale, unsigned short* As, unsigned short* Bs, int bm, int bn)
{
  const int t = threadIdx.x, wid = t >> 6, lane = t & 63;
  const int lrow = lane & 15, lg = lane >> 4;
  const int wm = (wid >> 1) * 64, wn = (wid & 1) * 64;

  floatx4 acc[4][4];
  #pragma unroll
  for (int i = 0; i < 4; ++i)
    #pragma unroll
    for (int j = 0; j < 4; ++j) acc[i][j] = 0.0f;

  for (int k0 = 0; k0 < Dd; k0 += 32) {
    __syncthreads();
    #pragma unroll
    for (int half = 0; half < 2; ++half) {
      const int cidx = t + half * 256;
      const int r = cidx >> 2, c = cidx & 3;
      {
        const float* ga = X + (size_t)(bm * 128 + r) * Dd + k0 + c * 8;
        const floatx4 x0 = *(const floatx4*)ga;
        const floatx4 x1 = *(const floatx4*)(ga + 4);
        short8 va;
        #pragma unroll
        for (int j = 0; j < 4; ++j) { va[j] = (short)f2bf(x0[j]); va[4+j] = (short)f2bf(x1[j]); }
        *(short8*)&As[r * APAD + c * 8] = va;
      }
      {
        const float* gb = W + (size_t)(bn * 128 + r) * Dd + k0 + c * 8;
        const floatx4 x0 = *(const floatx4*)gb;
        const floatx4 x1 = *(const floatx4*)(gb + 4);
        short8 vb;
        #pragma unroll
        for (int j = 0; j < 4; ++j) { vb[j] = (short)f2bf(x0[j]); vb[4+j] = (short)f2bf(x1[j]); }
        *(short8*)&Bs[r * APAD + c * 8] = vb;
      }
    }
    __syncthreads();

    bf16x8 af[4], bf[4];
    #pragma unroll
    for (int mi = 0; mi < 4; ++mi)
      af[mi] = __builtin_bit_cast(bf16x8, *(const short8*)&As[(wm + mi * 16 + lrow) * APAD + lg * 8]);
    #pragma unroll
    for (int ni = 0; ni < 4; ++ni)
      bf[ni] = __builtin_bit_cast(bf16x8, *(const short8*)&Bs[(wn + ni * 16 + lrow) * APAD + lg * 8]);

    #pragma unroll
    for (int mi = 0; mi < 4; ++mi)
      #pragma unroll
      for (int ni = 0; ni < 4; ++ni) {
        if constexpr (SWAP)
          acc[mi][ni] = __builtin_amdgcn_mfma_f32_16x16x32_bf16(bf[ni], af[mi], acc[mi][ni], 0, 0, 0);
        else
          acc[mi][ni] = __builtin_amdgcn_mfma_f32_16x16x32_bf16(af[mi], bf[ni], acc[mi][ni], 0, 0, 0);
      }
  }
  store_out<SWAP>(acc, bias, out, oscale, bm, bn, wm, wn, lrow, lg);
}

__global__ __launch_bounds__(256, 2) void qkv_gemm_f32(
    const float* __restrict__ q, const float* __restrict__ k, const float* __restrict__ v,
    const float* __restrict__ wq, const float* __restrict__ wk, const float* __restrict__ wv,
    const float* __restrict__ bq, const float* __restrict__ bk, const float* __restrict__ bv,
    unsigned short* __restrict__ outbase)
{
  __shared__ __align__(16) unsigned short As[128 * APAD];
  __shared__ __align__(16) unsigned short Bs[128 * APAD];

  const int id  = blockIdx.y * 256 + blockIdx.x;
  const int swz = (id & 7) * 96 + (id >> 3);
  const int sel = swz >> 8;
  const int bx  = swz & 255;
  const int bm = bx >> 3, bn = bx & 7;

  const float* X = sel == 0 ? q : sel == 1 ? k : v;
  const float* W = sel == 0 ? wq : sel == 1 ? wk : wv;
  const float* bias = sel == 0 ? bq : sel == 1 ? bk : bv;
  unsigned short* out = outbase + (size_t)sel * XE;

  if (sel == 2) gemm_core_f32<true >(X, W, bias, out, 1.0f, As, Bs, bm, bn);
  else          gemm_core_f32<false>(X, W, bias, out, sel == 0 ? QSCALE : 1.0f, As, Bs, bm, bn);
}

// ---------------------------------------------------------------------------
// Flash attention, 32x32 MFMA, LDS-staged (round-4 base) + 2-deep pipeline:
// per iteration compute PV(t) ∥ QK^T(t+1) (independent MFMA chains) with
// softmax(t+1) VALU overlapping PV(t).  V-frags of tile t are moved LDS->regs
// BEFORE the barrier so stage(t+2) can overwrite buf[t&1]; 1 barrier/tile.
// ---------------------------------------------------------------------------
constexpr int NT = Ss / 64;   // 32 kv tiles

__global__ __launch_bounds__(256, 2) void attn_fwd(
    const unsigned short* __restrict__ Qw, const unsigned short* __restrict__ Kw,
    const unsigned short* __restrict__ Vw, float* __restrict__ out)
{
  __shared__ __align__(16) unsigned short Ks[2][64 * 64];   // [kv][hd], chunk^=(kv&7)
  __shared__ __align__(16) unsigned short Vt[2][64 * 64];   // [hd][kv], chunk^=(hd&7)

  // XCD-bijective swizzle: 512 blocks -> 64-contiguous per XCD.
  const int id  = blockIdx.y * 16 + blockIdx.x;
  const int swz = (id & 7) * 64 + (id >> 3);
  const int qb  = swz & 15, bh = swz >> 4;
  const int b   = bh >> 4, h = bh & 15;

  const int t = threadIdx.x, wid = t >> 6, lane = t & 63;
  const int l31 = lane & 31, hi = lane >> 5;
  const unsigned short* Qb = Qw + (size_t)bh * (Ss * HD);
  const unsigned short* Kb = Kw + (size_t)bh * (Ss * HD);
  const unsigned short* Vg = Vw + (size_t)(h * 64) * Mrows + b * Ss;   // row=hd
  const int q0 = qb * 128 + wid * 32;

  // Q B-fragments: lane holds Q[q=l31][hd = hs*16 + hi*8 + j]
  bf16x8 qf[4];
  #pragma unroll
  for (int hs = 0; hs < 4; ++hs)
    qf[hs] = __builtin_bit_cast(bf16x8,
        *(const short8*)(Qb + (size_t)(q0 + l31) * 64 + hs * 16 + hi * 8));

  floatx16 ctx[2], lsum;
  ctx[0] = 0.0f; ctx[1] = 0.0f; lsum = 0.0f;

  short8 ones_s;
  #pragma unroll
  for (int j = 0; j < 8; ++j) ones_s[j] = (short)0x3F80;   // bf16 1.0
  const bf16x8 ones = __builtin_bit_cast(bf16x8, ones_s);

  // Staging: wave wid covers rows wid*16 .. wid*16+15 of both tensors.
  const int rl = lane >> 3;                  // 0..7 within 8-row group
  const int cs = (lane & 7) ^ rl;            // pre-swizzled source chunk
  auto stage = [&](int T) {                  // tile index T -> buf T&1
    const int kv0 = T * 64, buf = T & 1;
    #pragma unroll
    for (int i = 0; i < 2; ++i) {
      const int row = wid * 16 + i * 8 + rl;
      gload16(Kb + (size_t)(kv0 + row) * 64 + cs * 8, &Ks[buf][(wid * 16 + i * 8) * 64]);
      gload16(Vg + (size_t)row * Mrows + kv0 + cs * 8, &Vt[buf][(wid * 16 + i * 8) * 64]);
    }
  };

  // QK^T(T) + softmax -> packed A-fragments pa[0..3] (ks = kv 16-step)
  auto qk_soft = [&](int T, uintx4 (&pa)[4]) {
    const int cur = T & 1;
    floatx16 s[2];
    s[0] = 0.0f; s[1] = 0.0f;
    __builtin_amdgcn_s_setprio(1);
    #pragma unroll
    for (int kvb = 0; kvb < 2; ++kvb)
      #pragma unroll
      for (int hs = 0; hs < 4; ++hs) {
        const int ch = ((hs << 1) | hi) ^ (l31 & 7);
        const bf16x8 kf = __builtin_bit_cast(bf16x8,
            *(const short8*)&Ks[cur][(kvb * 32 + l31) * 64 + (ch << 3)]);
        s[kvb] = __builtin_amdgcn_mfma_f32_32x32x16_bf16(kf, qf[hs], s[kvb], 0, 0, 0);
      }
    __builtin_amdgcn_s_setprio(0);

    #pragma unroll
    for (int kvb = 0; kvb < 2; ++kvb) {
      float p[16];
      #pragma unroll
      for (int r = 0; r < 16; ++r) p[r] = fexp2(s[kvb][r]);
      unsigned int c[8];
      #pragma unroll
      for (int i = 0; i < 8; ++i)
        asm("v_cvt_pk_bf16_f32 %0, %1, %2" : "=v"(c[i]) : "v"(p[2 * i]), "v"(p[2 * i + 1]));
      #pragma unroll
      for (int ks2 = 0; ks2 < 2; ++ks2) {
        unsigned int w0 = c[4 * ks2 + 0], w2 = c[4 * ks2 + 2];
        unsigned int w1 = c[4 * ks2 + 1], w3 = c[4 * ks2 + 3];
        asm("v_permlane32_swap_b32 %0, %1" : "+v"(w0), "+v"(w2));
        asm("v_permlane32_swap_b32 %0, %1" : "+v"(w1), "+v"(w3));
        uintx4 paw; paw[0] = w0; paw[1] = w1; paw[2] = w2; paw[3] = w3;
        pa[kvb * 2 + ks2] = paw;
      }
    }
  };

  // One pipeline step: PV(t) with paC + V(t); QK+softmax(t+1) -> paN.
  auto body = [&](int t_, uintx4 (&paC)[4], uintx4 (&paN)[4]) {
    const int cur = t_ & 1;
    // V fragments of tile t -> registers (before barrier; buf gets overwritten)
    bf16x8 vb[8];
    #pragma unroll
    for (int nb = 0; nb < 2; ++nb)
      #pragma unroll
      for (int ks = 0; ks < 4; ++ks) {
        const int ch = ((ks << 1) | hi) ^ (l31 & 7);
        vb[nb * 4 + ks] = __builtin_bit_cast(bf16x8,
            *(const short8*)&Vt[cur][(nb * 32 + l31) * 64 + (ch << 3)]);
      }
    __syncthreads();                         // all waves done reading buf[cur]; stage(t+1) landed
    if (t_ + 2 < NT) stage(t_ + 2);          // overwrite buf[cur] (K consumed, V in regs)
    if (t_ + 1 < NT) qk_soft(t_ + 1, paN);   // independent of PV(t)

    // PV(t): 12 MFMA on paC/vb (register-only, overlaps qk_soft's VALU)
    __builtin_amdgcn_s_setprio(1);
    #pragma unroll
    for (int ks = 0; ks < 4; ++ks) {
      const bf16x8 pab = __builtin_bit_cast(bf16x8, paC[ks]);
      lsum   = __builtin_amdgcn_mfma_f32_32x32x16_bf16(pab, ones,       lsum,   0, 0, 0);
      ctx[0] = __builtin_amdgcn_mfma_f32_32x32x16_bf16(pab, vb[ks],     ctx[0], 0, 0, 0);
      ctx[1] = __builtin_amdgcn_mfma_f32_32x32x16_bf16(pab, vb[4 + ks], ctx[1], 0, 0, 0);
    }
    __builtin_amdgcn_s_setprio(0);
  };

  // Prologue: stage tiles 0,1; QK+softmax(0).
  stage(0);
  stage(1);
  __syncthreads();
  uintx4 paA[4], paB[4];
  qk_soft(0, paA);

  for (int it = 0; it < NT; it += 2) {       // static 2-step: no dynamic reg indexing
    body(it,     paA, paB);
    body(it + 1, paB, paA);
  }

  // ---- epilogue: normalize, write context [B,H,S,HD] + attn_output [B,S,D] ----
  #pragma unroll
  for (int r = 0; r < 16; ++r) {
    const float inv = 1.0f / lsum[r];
    const int qrow = q0 + (r & 3) + 8 * (r >> 2) + 4 * hi;
    #pragma unroll
    for (int nb = 0; nb < 2; ++nb) {
      const int hd = nb * 32 + l31;
      const float val = ctx[nb][r] * inv;
      out[((size_t)bh * Ss + qrow) * 64 + hd] = val;
      out[CTX_ELEMS + (((size_t)(b * Ss + qrow)) << 10) + (h << 6) + hd] = val;
    }
  }
}

// ---------------------------------------------------------------------------
extern "C" void kernel_launch(void* const* d_in, const int* in_sizes, int n_in,
                              void* d_out, int out_size, void* d_ws, size_t ws_size,
                              hipStream_t stream) {
  const float* q  = (const float*)d_in[0];
  const float* k  = (const float*)d_in[1];
  const float* v  = (const float*)d_in[2];
  const float* wq = (const float*)d_in[3];
  const float* bq = (const float*)d_in[4];
  const float* wk = (const float*)d_in[5];
  const float* bk = (const float*)d_in[6];
  const float* wv = (const float*)d_in[7];
  const float* bv = (const float*)d_in[8];
  unsigned short* ws = (unsigned short*)d_ws;
  float* out = (float*)d_out;

  if (ws_size >= WS_NEED) {
    convert_bf16<<<dim3(256, 6), 256, 0, stream>>>(q, k, v, wq, wk, wv, ws);
    qkv_gemm_bf16<<<dim3(256, 3), 256, 0, stream>>>(ws, bq, bk, bv, ws + OFF_O);
    attn_fwd<<<dim3(16, 32), 256, 0, stream>>>(ws + OFF_O, ws + OFF_O + XE, ws + OFF_O + 2 * XE, out);
  } else {
    qkv_gemm_f32<<<dim3(256, 3), 256, 0, stream>>>(q, k, v, wq, wk, wv, bq, bk, bv, ws);
    attn_fwd<<<dim3(16, 32), 256, 0, stream>>>(ws, ws + XE, ws + 2 * XE, out);
  }
}